// Round 5
// baseline (3174.180 us; speedup 1.0000x reference)
//
#include <hip/hip_runtime.h>
#include <hip/hip_bf16.h>

// TinyLocalWindowAttention on MI355X (gfx950)
// x:(32,256,112,112) f32, 7x7 windows, 8192 windows; 1 block (4 waves) per window.
// bf16 MFMA 16x16x32. LDS 32KB -> 5 blocks/CU.
// FUSED=1: block writes post-proj output bf16 window-major (coalesced) to ws;
//   the 16th-arriving block of each (b,wh) 16-window row band transforms the
//   band to f32 (B,C,H,W) with full-cache-line float4 writes (kills the
//   partial-line write amplification measured in rounds 2-4).
// FUSED=0 fallback (small ws): round-4 direct scatter store.

typedef short bf16x8 __attribute__((ext_vector_type(8)));   // 8 bf16 (4 VGPRs)
typedef float f32x4 __attribute__((ext_vector_type(4)));

static __device__ __forceinline__ unsigned short cvt1(float f) {
    __hip_bfloat16 h = __float2bfloat16(f);
    unsigned short u; __builtin_memcpy(&u, &h, 2); return u;
}
static __device__ __forceinline__ unsigned int cvt2(float a, float b) {
    float2 t; t.x = a; t.y = b;
    __hip_bfloat162 h = __float22bfloat162_rn(t);
    unsigned int u; __builtin_memcpy(&u, &h, 4); return u;
}
static __device__ __forceinline__ float bf2f(unsigned int hs) {
    return __uint_as_float(hs << 16);
}

#define XW_ELEMS 102760448LL                 // 8192 windows * 49*256 bf16 (ow buffer)
#define WQ_ELEMS 65536LL
#define WP_ELEMS 32768LL
#define CNT_OFF  ((XW_ELEMS + WQ_ELEMS + WP_ELEMS) * 2)   // byte offset of counters
#define WS_NEED  (CNT_OFF + 512 * 4)

// ---- pre-pass: Wqkv[256][256], Wproj[128][256] f32 -> bf16 B-fragment arrays ----
__global__ void prep_weights(const float* __restrict__ Wqkv,
                             const float* __restrict__ Wproj,
                             unsigned short* __restrict__ wq,
                             unsigned short* __restrict__ wp) {
    int tid = blockIdx.x * 256 + threadIdx.x;
    if (tid < 8192) {                         // 16 ntiles * 8 ktiles * 64 lanes
        int lane = tid & 63, f = tid >> 6;
        int kt = f & 7, nt = f >> 3;
        int kbase = kt * 32 + (lane >> 4) * 8;
        int col = nt * 16 + (lane & 15);
        uint4 u;
        u.x = cvt2(Wqkv[(kbase + 0) * 256 + col], Wqkv[(kbase + 1) * 256 + col]);
        u.y = cvt2(Wqkv[(kbase + 2) * 256 + col], Wqkv[(kbase + 3) * 256 + col]);
        u.z = cvt2(Wqkv[(kbase + 4) * 256 + col], Wqkv[(kbase + 5) * 256 + col]);
        u.w = cvt2(Wqkv[(kbase + 6) * 256 + col], Wqkv[(kbase + 7) * 256 + col]);
        *reinterpret_cast<uint4*>(&wq[(long long)tid * 8]) = u;
    } else if (tid < 12288) {                 // 16 ntiles * 4 ktiles * 64 lanes
        int i2 = tid - 8192;
        int lane = i2 & 63, f = i2 >> 6;
        int kt = f & 3, nt = f >> 2;
        int kbase = kt * 32 + (lane >> 4) * 8;
        int col = nt * 16 + (lane & 15);
        uint4 u;
        u.x = cvt2(Wproj[(kbase + 0) * 256 + col], Wproj[(kbase + 1) * 256 + col]);
        u.y = cvt2(Wproj[(kbase + 2) * 256 + col], Wproj[(kbase + 3) * 256 + col]);
        u.z = cvt2(Wproj[(kbase + 4) * 256 + col], Wproj[(kbase + 5) * 256 + col]);
        u.w = cvt2(Wproj[(kbase + 6) * 256 + col], Wproj[(kbase + 7) * 256 + col]);
        *reinterpret_cast<uint4*>(&wp[(long long)i2 * 8]) = u;
    }
}

// LDS (32 KB -> 5 blocks/CU):
//  A: xa[64][256] -> { q[64][64]@0, k[64][64]@4096, vT[4][32][64]@8192 }
//     -> o_s[64][128]@0 -> out_s[64][256] -> (FUSED) tail flag @A[0]
// swizzle: elem(row,col,W) = row*W + (((col>>3) ^ (row&7))<<3) + (col&7)

template <int FUSED>
__global__ __launch_bounds__(256, 5) void win_attn(
    const float* __restrict__ x,
    const unsigned short* __restrict__ wfq,
    const unsigned short* __restrict__ wfp,
    const float* __restrict__ bqkv,
    const float* __restrict__ bproj,
    float* __restrict__ out,
    unsigned short* __restrict__ ow,
    unsigned int* __restrict__ cnt)
{
    __shared__ __align__(16) unsigned short A[16384];

    const int tid  = threadIdx.x;
    const int lane = tid & 63;
    const int wave = tid >> 6;
    const int lr   = lane & 15;       // row/col within 16-tile
    const int kg   = lane >> 4;       // k-group (0..3)

    // XCD swizzle: contiguous 1024 windows per XCD
    const int bid = (int)blockIdx.x;
    const int L   = (bid & 7) * 1024 + (bid >> 3);
    const int b   = L >> 8;
    const int rem = L & 255;
    const int h0 = (rem >> 4) * 7;
    const int w0 = (rem & 15) * 7;
    const int xwin = (b * 256) * 12544 + h0 * 112 + w0;

    // preload biases
    float bqv[4], bpv[4];
    #pragma unroll
    for (int nn = 0; nn < 4; ++nn) {
        bqv[nn] = bqkv[wave * 64 + nn * 16 + lr];
        bpv[nn] = bproj[wave * 64 + nn * 16 + lr];
    }

    // ---- phase A: zero pad rows 49..63, load x window -> xa (bf16) ----
    for (int i = tid; i < 15 * 128; i += 256)
        reinterpret_cast<unsigned int*>(A)[49 * 128 + i] = 0u;

    if (lane < 49) {
        const int lb = xwin + (lane / 7) * 112 + (lane % 7);
        #pragma unroll 4
        for (int it = 0; it < 16; ++it) {
            const int c0 = wave * 64 + it * 4;
            const float v0 = x[lb + (c0 + 0) * 12544];
            const float v1 = x[lb + (c0 + 1) * 12544];
            const float v2 = x[lb + (c0 + 2) * 12544];
            const float v3 = x[lb + (c0 + 3) * 12544];
            uint2 pk; pk.x = cvt2(v0, v1); pk.y = cvt2(v2, v3);
            const int e = lane * 256 + (((c0 >> 3) ^ (lane & 7)) << 3) + (c0 & 7);
            *reinterpret_cast<uint2*>(&A[e]) = pk;
        }
    }
    __syncthreads();   // (1) xa ready

    // ---- phase B: qkv = xa @ Wqkv ; wave w owns output cols [64w, 64w+64) ----
    f32x4 acc[4][4];
    #pragma unroll
    for (int m = 0; m < 4; ++m)
        #pragma unroll
        for (int nn = 0; nn < 4; ++nn)
            acc[m][nn] = f32x4{0.f, 0.f, 0.f, 0.f};

    #pragma unroll
    for (int kt = 0; kt < 8; ++kt) {
        bf16x8 a[4], bw[4];
        #pragma unroll
        for (int m = 0; m < 4; ++m) {
            const int row = lr + 16 * m;
            const int ch  = (kt * 4 + kg) ^ (row & 7);
            a[m] = *reinterpret_cast<const bf16x8*>(&A[row * 256 + ch * 8]);
        }
        #pragma unroll
        for (int nn = 0; nn < 4; ++nn) {
            const int nt = wave * 4 + nn;
            bw[nn] = *reinterpret_cast<const bf16x8*>(&wfq[((nt * 8 + kt) * 64 + lane) * 8]);
        }
        #pragma unroll
        for (int m = 0; m < 4; ++m)
            #pragma unroll
            for (int nn = 0; nn < 4; ++nn)
                acc[m][nn] = __builtin_amdgcn_mfma_f32_16x16x32_bf16(a[m], bw[nn], acc[m][nn], 0, 0, 0);
    }
    __syncthreads();   // (2) all waves done READING xa (q/k/vT overlay it)

    // epilogue: +bias; wave0 -> q@A[0), wave1 -> k@A[4096), waves 2,3 -> vT@A[8192)
    #pragma unroll
    for (int nn = 0; nn < 4; ++nn) {
        const int colg = wave * 64 + nn * 16 + lr;
        #pragma unroll
        for (int m = 0; m < 4; ++m)
            #pragma unroll
            for (int r = 0; r < 4; ++r) {
                const int row = kg * 4 + r + 16 * m;        // token
                const unsigned short hv = cvt1(acc[m][nn][r] + bqv[nn]);
                if (wave < 2) {
                    const int c = colg & 63;
                    A[(wave << 12) + row * 64 + (((c >> 3) ^ (row & 7)) << 3) + (c & 7)] = hv;
                } else {
                    const int vc = colg - 128;
                    const int hh = vc >> 5, d = vc & 31;
                    A[8192 + hh * 2048 + d * 64 + (((row >> 3) ^ (d & 7)) << 3) + (row & 7)] = hv;
                }
            }
    }
    __syncthreads();   // (3) q/k/vT ready

    // ---- attention, head h = wave; S^T = mfma(K, Q): lane holds P^T col for
    //      one q-token: col=lane&15=q-token, row=4kg+r=k-token ----
    const int h = wave;
    const bf16x8 zf = {0, 0, 0, 0, 0, 0, 0, 0};

    bf16x8 kf[4];
    #pragma unroll
    for (int km = 0; km < 4; ++km) {
        if (lane < 32) {
            const int row = lr + 16 * km;
            kf[km] = *reinterpret_cast<const bf16x8*>(
                &A[4096 + row * 64 + (((h * 2 + kg) ^ (row & 7)) << 3)]);
        } else kf[km] = zf;
    }
    bf16x8 vb[2][2];
    #pragma unroll
    for (int kt = 0; kt < 2; ++kt)
        #pragma unroll
        for (int nt = 0; nt < 2; ++nt) {
            const int d = lr + 16 * nt;
            const int ch = (kt * 4 + kg) ^ (d & 7);
            vb[kt][nt] = *reinterpret_cast<const bf16x8*>(&A[8192 + h * 2048 + d * 64 + ch * 8]);
        }

    // bpermute source addresses (bytes): srclane = 16*((2kg+{0,1})&3) + lr
    const int a0 = (((kg & 1) * 2)     * 16 + lr) * 4;
    const int a1 = (((kg & 1) * 2 + 1) * 16 + lr) * 4;

    f32x4 oacc[4][2];
    #pragma unroll
    for (int qn = 0; qn < 4; ++qn) {
        oacc[qn][0] = f32x4{0.f, 0.f, 0.f, 0.f};
        oacc[qn][1] = f32x4{0.f, 0.f, 0.f, 0.f};
    }
    const float C = 0.25f * 1.44269504f;    // SCALE * log2(e)

    #pragma unroll
    for (int qn = 0; qn < 4; ++qn) {
        bf16x8 qf;
        if (lane < 32) {
            const int row = lr + 16 * qn;
            qf = *reinterpret_cast<const bf16x8*>(
                &A[row * 64 + (((h * 2 + kg) ^ (row & 7)) << 3)]);
        } else qf = zf;

        f32x4 s[4];
        #pragma unroll
        for (int km = 0; km < 4; ++km) {
            f32x4 z = f32x4{0.f, 0.f, 0.f, 0.f};
            s[km] = __builtin_amdgcn_mfma_f32_16x16x32_bf16(kf[km], qf, z, 0, 0, 0);
        }

        float e[4][4];
        float sum = 0.f;
        #pragma unroll
        for (int km = 0; km < 4; ++km)
            #pragma unroll
            for (int r = 0; r < 4; ++r) {
                float v = __builtin_amdgcn_exp2f(s[km][r] * C);
                if (km == 3 && !(kg == 0 && r == 0)) v = 0.f;   // k-token 48 only
                e[km][r] = v;
                sum += v;
            }
        sum += __shfl_xor(sum, 16, 64);
        sum += __shfl_xor(sum, 32, 64);
        const float rs = __builtin_amdgcn_rcpf(sum);

        unsigned int D[4][2];
        #pragma unroll
        for (int km = 0; km < 4; ++km) {
            D[km][0] = cvt2(e[km][0] * rs, e[km][1] * rs);
            D[km][1] = cvt2(e[km][2] * rs, e[km][3] * rs);
        }

        #pragma unroll
        for (int kt = 0; kt < 2; ++kt) {
            const int klo = 2 * kt, khi = 2 * kt + 1;
            const unsigned int t0 = (unsigned)__builtin_amdgcn_ds_bpermute(a0, (int)D[klo][0]);
            const unsigned int u0 = (unsigned)__builtin_amdgcn_ds_bpermute(a0, (int)D[khi][0]);
            const unsigned int t1 = (unsigned)__builtin_amdgcn_ds_bpermute(a0, (int)D[klo][1]);
            const unsigned int u1 = (unsigned)__builtin_amdgcn_ds_bpermute(a0, (int)D[khi][1]);
            const unsigned int t2 = (unsigned)__builtin_amdgcn_ds_bpermute(a1, (int)D[klo][0]);
            const unsigned int u2 = (unsigned)__builtin_amdgcn_ds_bpermute(a1, (int)D[khi][0]);
            const unsigned int t3 = (unsigned)__builtin_amdgcn_ds_bpermute(a1, (int)D[klo][1]);
            const unsigned int u3 = (unsigned)__builtin_amdgcn_ds_bpermute(a1, (int)D[khi][1]);
            union { unsigned int u[4]; bf16x8 v; } pu;
            pu.u[0] = (kg < 2) ? t0 : u0;
            pu.u[1] = (kg < 2) ? t1 : u1;
            pu.u[2] = (kg < 2) ? t2 : u2;
            pu.u[3] = (kg < 2) ? t3 : u3;
            oacc[qn][0] = __builtin_amdgcn_mfma_f32_16x16x32_bf16(pu.v, vb[kt][0], oacc[qn][0], 0, 0, 0);
            oacc[qn][1] = __builtin_amdgcn_mfma_f32_16x16x32_bf16(pu.v, vb[kt][1], oacc[qn][1], 0, 0, 0);
        }
    }

    __syncthreads();   // (4) q/k reads done -> o_s overlays A[0..8192)

    #pragma unroll
    for (int qn = 0; qn < 4; ++qn)
        #pragma unroll
        for (int nt = 0; nt < 2; ++nt)
            #pragma unroll
            for (int r = 0; r < 4; ++r) {
                const int row = kg * 4 + r + 16 * qn;
                const int col = h * 32 + nt * 16 + lr;
                A[row * 128 + (((col >> 3) ^ (row & 7)) << 3) + (col & 7)] =
                    cvt1(oacc[qn][nt][r]);
            }
    __syncthreads();   // (5) o_s ready

    // ---- proj: out = o_s @ Wproj + bproj ----
    f32x4 pc[4][4];
    #pragma unroll
    for (int m = 0; m < 4; ++m)
        #pragma unroll
        for (int nn = 0; nn < 4; ++nn)
            pc[m][nn] = f32x4{0.f, 0.f, 0.f, 0.f};

    #pragma unroll
    for (int kt = 0; kt < 4; ++kt) {
        bf16x8 a[4], bw[4];
        #pragma unroll
        for (int m = 0; m < 4; ++m) {
            const int row = lr + 16 * m;
            const int ch = (kt * 4 + kg) ^ (row & 7);
            a[m] = *reinterpret_cast<const bf16x8*>(&A[row * 128 + ch * 8]);
        }
        #pragma unroll
        for (int nn = 0; nn < 4; ++nn) {
            const int nt = wave * 4 + nn;
            bw[nn] = *reinterpret_cast<const bf16x8*>(&wfp[((nt * 4 + kt) * 64 + lane) * 8]);
        }
        #pragma unroll
        for (int m = 0; m < 4; ++m)
            #pragma unroll
            for (int nn = 0; nn < 4; ++nn)
                pc[m][nn] = __builtin_amdgcn_mfma_f32_16x16x32_bf16(a[m], bw[nn], pc[m][nn], 0, 0, 0);
    }
    __syncthreads();   // (6) proj reads done -> out_s overlays everything

    // write out_s[64][256] into A
    #pragma unroll
    for (int nn = 0; nn < 4; ++nn) {
        const int colg = wave * 64 + nn * 16 + lr;
        #pragma unroll
        for (int m = 0; m < 4; ++m)
            #pragma unroll
            for (int r = 0; r < 4; ++r) {
                const int row = kg * 4 + r + 16 * m;
                A[row * 256 + (((colg >> 3) ^ (row & 7)) << 3) + (colg & 7)] = cvt1(pc[m][nn][r] + bpv[nn]);
            }
    }

    if constexpr (FUSED) {
        __syncthreads();   // (7) out_s complete for all waves

        // coalesced bf16 store of this window's 49x256 output to ws
        const long long slot = (long long)L * 12544;
        for (int u = tid; u < 1568; u += 256) {
            const int tok = u >> 5, cu = u & 31;
            const uint4 d = *reinterpret_cast<const uint4*>(
                &A[tok * 256 + ((cu ^ (tok & 7)) << 3)]);
            *reinterpret_cast<uint4*>(&ow[slot + u * 8]) = d;
        }

        // band completion: 16 windows per (b,wh) row band; last arriver transforms
        __threadfence();
        __syncthreads();
        if (tid == 0) {
            const unsigned prev = atomicAdd(&cnt[L >> 4], 1u);
            *reinterpret_cast<int*>(&A[0]) = (prev == 15u) ? 1 : 0;
        }
        __syncthreads();
        if (*reinterpret_cast<const int*>(&A[0])) {
            __threadfence();   // acquire: see sibling blocks' ow writes
            const int band = L >> 4;
            const int bb = band >> 4, wh = band & 15;
            const long long wbase = (long long)(band << 4) * 12544;
            const int cq = tid & 63, ps = tid >> 6;
            for (int i = 0; i < 49; ++i) {
                const int pos = ps * 49 + i;
                const int r = pos / 28, w4 = pos % 28;
                float4 v[4];
                #pragma unroll
                for (int j = 0; j < 4; ++j) {
                    const int w = w4 * 4 + j;
                    const int win = w / 7;
                    const int tok = r * 7 + (w - win * 7);
                    const uint2 dv = *reinterpret_cast<const uint2*>(
                        &ow[wbase + (long long)win * 12544 + tok * 256 + cq * 4]);
                    v[0][j] = bf2f(dv.x & 0xffffu);
                    v[1][j] = bf2f(dv.x >> 16);
                    v[2][j] = bf2f(dv.y & 0xffffu);
                    v[3][j] = bf2f(dv.y >> 16);
                }
                float* op = out + ((long long)bb * 256 + cq * 4) * 12544
                                + (wh * 7 + r) * 112 + w4 * 4;
                #pragma unroll
                for (int p = 0; p < 4; ++p)
                    *reinterpret_cast<float4*>(op + (long long)p * 12544) = v[p];
            }
        }
    } else {
        __builtin_amdgcn_wave_barrier();
        // direct scatter store (fallback): wave-own cols
        if (lane < 49) {
            const int lb = xwin + (lane / 7) * 112 + (lane % 7);
            #pragma unroll 4
            for (int it = 0; it < 16; ++it) {
                const int c0 = wave * 64 + it * 4;
                const int e = lane * 256 + (((c0 >> 3) ^ (lane & 7)) << 3) + (c0 & 7);
                const uint2 pk = *reinterpret_cast<const uint2*>(&A[e]);
                out[lb + (c0 + 0) * 12544] = bf2f(pk.x & 0xffffu);
                out[lb + (c0 + 1) * 12544] = bf2f(pk.x >> 16);
                out[lb + (c0 + 2) * 12544] = bf2f(pk.y & 0xffffu);
                out[lb + (c0 + 3) * 12544] = bf2f(pk.y >> 16);
            }
        }
    }
}

extern "C" void kernel_launch(void* const* d_in, const int* in_sizes, int n_in,
                              void* d_out, int out_size, void* d_ws, size_t ws_size,
                              hipStream_t stream) {
    const float* x     = (const float*)d_in[0];
    const float* Wqkv  = (const float*)d_in[1];
    const float* bqkv  = (const float*)d_in[2];
    const float* Wproj = (const float*)d_in[3];
    const float* bproj = (const float*)d_in[4];
    float* out = (float*)d_out;

    if (ws_size >= (size_t)WS_NEED) {
        unsigned short* ow  = (unsigned short*)d_ws;
        unsigned short* wfq = ow + XW_ELEMS;
        unsigned short* wfp = wfq + WQ_ELEMS;
        unsigned int*   cnt = (unsigned int*)((char*)d_ws + CNT_OFF);
        hipMemsetAsync(cnt, 0, 512 * sizeof(unsigned int), stream);
        prep_weights<<<48, 256, 0, stream>>>(Wqkv, Wproj, wfq, wfp);
        win_attn<1><<<8192, 256, 0, stream>>>(x, wfq, wfp, bqkv, bproj, out, ow, cnt);
    } else {
        unsigned short* wfq = (unsigned short*)d_ws;
        unsigned short* wfp = wfq + WQ_ELEMS;
        prep_weights<<<48, 256, 0, stream>>>(Wqkv, Wproj, wfq, wfp);
        win_attn<0><<<8192, 256, 0, stream>>>(x, wfq, wfp, bqkv, bproj, out,
                                              wfq /*unused*/, (unsigned int*)wfq /*unused*/);
    }
}

// Round 6
// 1422.393 us; speedup vs baseline: 2.2316x; 2.2316x over previous
//
#include <hip/hip_runtime.h>
#include <hip/hip_bf16.h>

// TinyLocalWindowAttention on MI355X (gfx950)
// x:(32,256,112,112) f32, 7x7 windows, 8192 windows; 1 block (4 waves) per window.
// bf16 MFMA 16x16x32. LDS 32KB -> 5 blocks/CU.
// Round 6: decoupled output path.
//   win_attn  : compute, writes window-major bf16 (coalesced 25KB/window) to ws.
//   band_merge: spreads the layout transform over 2048 blocks; scattered 4B
//               L3-resident reads, FULL-LINE float4 writes (fixes the 4x write
//               amplification measured in rounds 4-5).
// FUSED=0 fallback (small ws): round-4 direct scatter store.

typedef short bf16x8 __attribute__((ext_vector_type(8)));   // 8 bf16 (4 VGPRs)
typedef float f32x4 __attribute__((ext_vector_type(4)));

static __device__ __forceinline__ unsigned short cvt1(float f) {
    __hip_bfloat16 h = __float2bfloat16(f);
    unsigned short u; __builtin_memcpy(&u, &h, 2); return u;
}
static __device__ __forceinline__ unsigned int cvt2(float a, float b) {
    float2 t; t.x = a; t.y = b;
    __hip_bfloat162 h = __float22bfloat162_rn(t);
    unsigned int u; __builtin_memcpy(&u, &h, 4); return u;
}
static __device__ __forceinline__ float bf2f(unsigned int hs) {
    return __uint_as_float(hs << 16);
}

#define XW_ELEMS 102760448LL                 // 8192 windows * 49*256 bf16 (ow buffer)
#define WQ_ELEMS 65536LL
#define WP_ELEMS 32768LL
#define WS_NEED  ((XW_ELEMS + WQ_ELEMS + WP_ELEMS) * 2)

// ---- pre-pass: Wqkv[256][256], Wproj[128][256] f32 -> bf16 B-fragment arrays ----
__global__ void prep_weights(const float* __restrict__ Wqkv,
                             const float* __restrict__ Wproj,
                             unsigned short* __restrict__ wq,
                             unsigned short* __restrict__ wp) {
    int tid = blockIdx.x * 256 + threadIdx.x;
    if (tid < 8192) {                         // 16 ntiles * 8 ktiles * 64 lanes
        int lane = tid & 63, f = tid >> 6;
        int kt = f & 7, nt = f >> 3;
        int kbase = kt * 32 + (lane >> 4) * 8;
        int col = nt * 16 + (lane & 15);
        uint4 u;
        u.x = cvt2(Wqkv[(kbase + 0) * 256 + col], Wqkv[(kbase + 1) * 256 + col]);
        u.y = cvt2(Wqkv[(kbase + 2) * 256 + col], Wqkv[(kbase + 3) * 256 + col]);
        u.z = cvt2(Wqkv[(kbase + 4) * 256 + col], Wqkv[(kbase + 5) * 256 + col]);
        u.w = cvt2(Wqkv[(kbase + 6) * 256 + col], Wqkv[(kbase + 7) * 256 + col]);
        *reinterpret_cast<uint4*>(&wq[(long long)tid * 8]) = u;
    } else if (tid < 12288) {                 // 16 ntiles * 4 ktiles * 64 lanes
        int i2 = tid - 8192;
        int lane = i2 & 63, f = i2 >> 6;
        int kt = f & 3, nt = f >> 2;
        int kbase = kt * 32 + (lane >> 4) * 8;
        int col = nt * 16 + (lane & 15);
        uint4 u;
        u.x = cvt2(Wproj[(kbase + 0) * 256 + col], Wproj[(kbase + 1) * 256 + col]);
        u.y = cvt2(Wproj[(kbase + 2) * 256 + col], Wproj[(kbase + 3) * 256 + col]);
        u.z = cvt2(Wproj[(kbase + 4) * 256 + col], Wproj[(kbase + 5) * 256 + col]);
        u.w = cvt2(Wproj[(kbase + 6) * 256 + col], Wproj[(kbase + 7) * 256 + col]);
        *reinterpret_cast<uint4*>(&wp[(long long)i2 * 8]) = u;
    }
}

// LDS (32 KB -> 5 blocks/CU):
//  A: xa[64][256] -> { q[64][64]@0, k[64][64]@4096, vT[4][32][64]@8192 }
//     -> o_s[64][128]@0 -> out_s[64][256]
// swizzle: elem(row,col,W) = row*W + (((col>>3) ^ (row&7))<<3) + (col&7)

template <int FUSED>
__global__ __launch_bounds__(256, 5) void win_attn(
    const float* __restrict__ x,
    const unsigned short* __restrict__ wfq,
    const unsigned short* __restrict__ wfp,
    const float* __restrict__ bqkv,
    const float* __restrict__ bproj,
    float* __restrict__ out,
    unsigned short* __restrict__ ow)
{
    __shared__ __align__(16) unsigned short A[16384];

    const int tid  = threadIdx.x;
    const int lane = tid & 63;
    const int wave = tid >> 6;
    const int lr   = lane & 15;       // row/col within 16-tile
    const int kg   = lane >> 4;       // k-group (0..3)

    // XCD swizzle: contiguous 1024 windows per XCD
    const int bid = (int)blockIdx.x;
    const int L   = (bid & 7) * 1024 + (bid >> 3);
    const int b   = L >> 8;
    const int rem = L & 255;
    const int h0 = (rem >> 4) * 7;
    const int w0 = (rem & 15) * 7;
    const int xwin = (b * 256) * 12544 + h0 * 112 + w0;

    // preload biases
    float bqv[4], bpv[4];
    #pragma unroll
    for (int nn = 0; nn < 4; ++nn) {
        bqv[nn] = bqkv[wave * 64 + nn * 16 + lr];
        bpv[nn] = bproj[wave * 64 + nn * 16 + lr];
    }

    // ---- phase A: zero pad rows 49..63, load x window -> xa (bf16) ----
    for (int i = tid; i < 15 * 128; i += 256)
        reinterpret_cast<unsigned int*>(A)[49 * 128 + i] = 0u;

    if (lane < 49) {
        const int lb = xwin + (lane / 7) * 112 + (lane % 7);
        #pragma unroll 4
        for (int it = 0; it < 16; ++it) {
            const int c0 = wave * 64 + it * 4;
            const float v0 = x[lb + (c0 + 0) * 12544];
            const float v1 = x[lb + (c0 + 1) * 12544];
            const float v2 = x[lb + (c0 + 2) * 12544];
            const float v3 = x[lb + (c0 + 3) * 12544];
            uint2 pk; pk.x = cvt2(v0, v1); pk.y = cvt2(v2, v3);
            const int e = lane * 256 + (((c0 >> 3) ^ (lane & 7)) << 3) + (c0 & 7);
            *reinterpret_cast<uint2*>(&A[e]) = pk;
        }
    }
    __syncthreads();   // (1) xa ready

    // ---- phase B: qkv = xa @ Wqkv ; wave w owns output cols [64w, 64w+64) ----
    f32x4 acc[4][4];
    #pragma unroll
    for (int m = 0; m < 4; ++m)
        #pragma unroll
        for (int nn = 0; nn < 4; ++nn)
            acc[m][nn] = f32x4{0.f, 0.f, 0.f, 0.f};

    #pragma unroll
    for (int kt = 0; kt < 8; ++kt) {
        bf16x8 a[4], bw[4];
        #pragma unroll
        for (int m = 0; m < 4; ++m) {
            const int row = lr + 16 * m;
            const int ch  = (kt * 4 + kg) ^ (row & 7);
            a[m] = *reinterpret_cast<const bf16x8*>(&A[row * 256 + ch * 8]);
        }
        #pragma unroll
        for (int nn = 0; nn < 4; ++nn) {
            const int nt = wave * 4 + nn;
            bw[nn] = *reinterpret_cast<const bf16x8*>(&wfq[((nt * 8 + kt) * 64 + lane) * 8]);
        }
        #pragma unroll
        for (int m = 0; m < 4; ++m)
            #pragma unroll
            for (int nn = 0; nn < 4; ++nn)
                acc[m][nn] = __builtin_amdgcn_mfma_f32_16x16x32_bf16(a[m], bw[nn], acc[m][nn], 0, 0, 0);
    }
    __syncthreads();   // (2) all waves done READING xa (q/k/vT overlay it)

    // epilogue: +bias; wave0 -> q@A[0), wave1 -> k@A[4096), waves 2,3 -> vT@A[8192)
    #pragma unroll
    for (int nn = 0; nn < 4; ++nn) {
        const int colg = wave * 64 + nn * 16 + lr;
        #pragma unroll
        for (int m = 0; m < 4; ++m)
            #pragma unroll
            for (int r = 0; r < 4; ++r) {
                const int row = kg * 4 + r + 16 * m;        // token
                const unsigned short hv = cvt1(acc[m][nn][r] + bqv[nn]);
                if (wave < 2) {
                    const int c = colg & 63;
                    A[(wave << 12) + row * 64 + (((c >> 3) ^ (row & 7)) << 3) + (c & 7)] = hv;
                } else {
                    const int vc = colg - 128;
                    const int hh = vc >> 5, d = vc & 31;
                    A[8192 + hh * 2048 + d * 64 + (((row >> 3) ^ (d & 7)) << 3) + (row & 7)] = hv;
                }
            }
    }
    __syncthreads();   // (3) q/k/vT ready

    // ---- attention, head h = wave; S^T = mfma(K, Q): lane holds P^T col for
    //      one q-token: col=lane&15=q-token, row=4kg+r=k-token ----
    const int h = wave;
    const bf16x8 zf = {0, 0, 0, 0, 0, 0, 0, 0};

    bf16x8 kf[4];
    #pragma unroll
    for (int km = 0; km < 4; ++km) {
        if (lane < 32) {
            const int row = lr + 16 * km;
            kf[km] = *reinterpret_cast<const bf16x8*>(
                &A[4096 + row * 64 + (((h * 2 + kg) ^ (row & 7)) << 3)]);
        } else kf[km] = zf;
    }
    bf16x8 vb[2][2];
    #pragma unroll
    for (int kt = 0; kt < 2; ++kt)
        #pragma unroll
        for (int nt = 0; nt < 2; ++nt) {
            const int d = lr + 16 * nt;
            const int ch = (kt * 4 + kg) ^ (d & 7);
            vb[kt][nt] = *reinterpret_cast<const bf16x8*>(&A[8192 + h * 2048 + d * 64 + ch * 8]);
        }

    // bpermute source addresses (bytes): srclane = 16*((2kg+{0,1})&3) + lr
    const int a0 = (((kg & 1) * 2)     * 16 + lr) * 4;
    const int a1 = (((kg & 1) * 2 + 1) * 16 + lr) * 4;

    f32x4 oacc[4][2];
    #pragma unroll
    for (int qn = 0; qn < 4; ++qn) {
        oacc[qn][0] = f32x4{0.f, 0.f, 0.f, 0.f};
        oacc[qn][1] = f32x4{0.f, 0.f, 0.f, 0.f};
    }
    const float C = 0.25f * 1.44269504f;    // SCALE * log2(e)

    #pragma unroll
    for (int qn = 0; qn < 4; ++qn) {
        bf16x8 qf;
        if (lane < 32) {
            const int row = lr + 16 * qn;
            qf = *reinterpret_cast<const bf16x8*>(
                &A[row * 64 + (((h * 2 + kg) ^ (row & 7)) << 3)]);
        } else qf = zf;

        f32x4 s[4];
        #pragma unroll
        for (int km = 0; km < 4; ++km) {
            f32x4 z = f32x4{0.f, 0.f, 0.f, 0.f};
            s[km] = __builtin_amdgcn_mfma_f32_16x16x32_bf16(kf[km], qf, z, 0, 0, 0);
        }

        float e[4][4];
        float sum = 0.f;
        #pragma unroll
        for (int km = 0; km < 4; ++km)
            #pragma unroll
            for (int r = 0; r < 4; ++r) {
                float v = __builtin_amdgcn_exp2f(s[km][r] * C);
                if (km == 3 && !(kg == 0 && r == 0)) v = 0.f;   // k-token 48 only
                e[km][r] = v;
                sum += v;
            }
        sum += __shfl_xor(sum, 16, 64);
        sum += __shfl_xor(sum, 32, 64);
        const float rs = __builtin_amdgcn_rcpf(sum);

        unsigned int D[4][2];
        #pragma unroll
        for (int km = 0; km < 4; ++km) {
            D[km][0] = cvt2(e[km][0] * rs, e[km][1] * rs);
            D[km][1] = cvt2(e[km][2] * rs, e[km][3] * rs);
        }

        #pragma unroll
        for (int kt = 0; kt < 2; ++kt) {
            const int klo = 2 * kt, khi = 2 * kt + 1;
            const unsigned int t0 = (unsigned)__builtin_amdgcn_ds_bpermute(a0, (int)D[klo][0]);
            const unsigned int u0 = (unsigned)__builtin_amdgcn_ds_bpermute(a0, (int)D[khi][0]);
            const unsigned int t1 = (unsigned)__builtin_amdgcn_ds_bpermute(a0, (int)D[klo][1]);
            const unsigned int u1 = (unsigned)__builtin_amdgcn_ds_bpermute(a0, (int)D[khi][1]);
            const unsigned int t2 = (unsigned)__builtin_amdgcn_ds_bpermute(a1, (int)D[klo][0]);
            const unsigned int u2 = (unsigned)__builtin_amdgcn_ds_bpermute(a1, (int)D[khi][0]);
            const unsigned int t3 = (unsigned)__builtin_amdgcn_ds_bpermute(a1, (int)D[klo][1]);
            const unsigned int u3 = (unsigned)__builtin_amdgcn_ds_bpermute(a1, (int)D[khi][1]);
            union { unsigned int u[4]; bf16x8 v; } pu;
            pu.u[0] = (kg < 2) ? t0 : u0;
            pu.u[1] = (kg < 2) ? t1 : u1;
            pu.u[2] = (kg < 2) ? t2 : u2;
            pu.u[3] = (kg < 2) ? t3 : u3;
            oacc[qn][0] = __builtin_amdgcn_mfma_f32_16x16x32_bf16(pu.v, vb[kt][0], oacc[qn][0], 0, 0, 0);
            oacc[qn][1] = __builtin_amdgcn_mfma_f32_16x16x32_bf16(pu.v, vb[kt][1], oacc[qn][1], 0, 0, 0);
        }
    }

    __syncthreads();   // (4) q/k reads done -> o_s overlays A[0..8192)

    #pragma unroll
    for (int qn = 0; qn < 4; ++qn)
        #pragma unroll
        for (int nt = 0; nt < 2; ++nt)
            #pragma unroll
            for (int r = 0; r < 4; ++r) {
                const int row = kg * 4 + r + 16 * qn;
                const int col = h * 32 + nt * 16 + lr;
                A[row * 128 + (((col >> 3) ^ (row & 7)) << 3) + (col & 7)] =
                    cvt1(oacc[qn][nt][r]);
            }
    __syncthreads();   // (5) o_s ready

    // ---- proj: out = o_s @ Wproj + bproj ----
    f32x4 pc[4][4];
    #pragma unroll
    for (int m = 0; m < 4; ++m)
        #pragma unroll
        for (int nn = 0; nn < 4; ++nn)
            pc[m][nn] = f32x4{0.f, 0.f, 0.f, 0.f};

    #pragma unroll
    for (int kt = 0; kt < 4; ++kt) {
        bf16x8 a[4], bw[4];
        #pragma unroll
        for (int m = 0; m < 4; ++m) {
            const int row = lr + 16 * m;
            const int ch = (kt * 4 + kg) ^ (row & 7);
            a[m] = *reinterpret_cast<const bf16x8*>(&A[row * 128 + ch * 8]);
        }
        #pragma unroll
        for (int nn = 0; nn < 4; ++nn) {
            const int nt = wave * 4 + nn;
            bw[nn] = *reinterpret_cast<const bf16x8*>(&wfp[((nt * 4 + kt) * 64 + lane) * 8]);
        }
        #pragma unroll
        for (int m = 0; m < 4; ++m)
            #pragma unroll
            for (int nn = 0; nn < 4; ++nn)
                pc[m][nn] = __builtin_amdgcn_mfma_f32_16x16x32_bf16(a[m], bw[nn], pc[m][nn], 0, 0, 0);
    }
    __syncthreads();   // (6) proj reads done -> out_s overlays everything

    // write out_s[64][256] into A
    #pragma unroll
    for (int nn = 0; nn < 4; ++nn) {
        const int colg = wave * 64 + nn * 16 + lr;
        #pragma unroll
        for (int m = 0; m < 4; ++m)
            #pragma unroll
            for (int r = 0; r < 4; ++r) {
                const int row = kg * 4 + r + 16 * m;
                A[row * 256 + (((colg >> 3) ^ (row & 7)) << 3) + (colg & 7)] = cvt1(pc[m][nn][r] + bpv[nn]);
            }
    }

    if constexpr (FUSED) {
        __syncthreads();   // (7) out_s complete for all waves
        // coalesced bf16 store of this window's 49x256 output (swizzled layout,
        // straight linear copy of A[0..25088B)) to ow[L]
        const long long slot = (long long)L * 12544;
        for (int u = tid; u < 1568; u += 256) {
            const uint4 d = *reinterpret_cast<const uint4*>(&A[u * 8]);
            *reinterpret_cast<uint4*>(&ow[slot + u * 8]) = d;
        }
    } else {
        __builtin_amdgcn_wave_barrier();
        // direct scatter store (fallback): wave-own cols
        if (lane < 49) {
            const int lb = xwin + (lane / 7) * 112 + (lane % 7);
            #pragma unroll 4
            for (int it = 0; it < 16; ++it) {
                const int c0 = wave * 64 + it * 4;
                const int e = lane * 256 + (((c0 >> 3) ^ (lane & 7)) << 3) + (c0 & 7);
                const uint2 pk = *reinterpret_cast<const uint2*>(&A[e]);
                out[lb + (c0 + 0) * 12544] = bf2f(pk.x & 0xffffu);
                out[lb + (c0 + 1) * 12544] = bf2f(pk.x >> 16);
                out[lb + (c0 + 2) * 12544] = bf2f(pk.y & 0xffffu);
                out[lb + (c0 + 3) * 12544] = bf2f(pk.y >> 16);
            }
        }
    }
}

// ---- K3: ow (window-major bf16, swizzled) -> out (B,C,H,W) f32, full-line writes.
// 2048 blocks: (band, part). band = 64 consecutive per XCD (matches win_attn's
// swizzle so ow reads are L2/L3-local). Lane = w4 position; each lane reads 4
// uints (2 packed channels) and writes two float4 rows -> 448B contiguous per
// half-wave, zero write amplification.
__global__ __launch_bounds__(256, 8) void band_merge(
    const unsigned short* __restrict__ ow,
    float* __restrict__ out)
{
    const int bid  = (int)blockIdx.x;
    const int xcd  = bid & 7;
    const int idx  = bid >> 3;                 // 0..255
    const int band = xcd * 64 + (idx >> 2);    // 0..511
    const int part = idx & 3;                  // 64-channel slice
    const int bb   = band >> 4;                // batch
    const int wh   = band & 15;                // window row
    const int w4   = threadIdx.x & 31;
    const int rg   = threadIdx.x >> 5;         // 0..7

    if (w4 >= 28) return;                      // 112 = 28 float4

    const int Lb = band * 16;
    for (int pass = 0; pass < 28; ++pass) {
        const int rr = pass * 8 + rg;          // 0..223: (cp, h)
        const int cp = rr / 7, hh = rr - cp * 7;
        const int c  = part * 64 + cp * 2;
        float4 va, vbb;
        #pragma unroll
        for (int j = 0; j < 4; ++j) {
            const int w   = w4 * 4 + j;
            const int win = w / 7;
            const int tok = hh * 7 + (w - win * 7);
            const int e = (Lb + win) * 12544 + tok * 256
                        + (((c >> 3) ^ (tok & 7)) << 3) + (c & 7);
            const unsigned int dv = *reinterpret_cast<const unsigned int*>(&ow[e]);
            va[j]  = bf2f(dv & 0xffffu);
            vbb[j] = bf2f(dv >> 16);
        }
        float* op = out + (bb * 256 + c) * 12544 + (wh * 7 + hh) * 112 + w4 * 4;
        *reinterpret_cast<float4*>(op) = va;
        *reinterpret_cast<float4*>(op + 12544) = vbb;
    }
}

extern "C" void kernel_launch(void* const* d_in, const int* in_sizes, int n_in,
                              void* d_out, int out_size, void* d_ws, size_t ws_size,
                              hipStream_t stream) {
    const float* x     = (const float*)d_in[0];
    const float* Wqkv  = (const float*)d_in[1];
    const float* bqkv  = (const float*)d_in[2];
    const float* Wproj = (const float*)d_in[3];
    const float* bproj = (const float*)d_in[4];
    float* out = (float*)d_out;

    if (ws_size >= (size_t)WS_NEED) {
        unsigned short* ow  = (unsigned short*)d_ws;
        unsigned short* wfq = ow + XW_ELEMS;
        unsigned short* wfp = wfq + WQ_ELEMS;
        prep_weights<<<48, 256, 0, stream>>>(Wqkv, Wproj, wfq, wfp);
        win_attn<1><<<8192, 256, 0, stream>>>(x, wfq, wfp, bqkv, bproj, out, ow);
        band_merge<<<2048, 256, 0, stream>>>(ow, out);
    } else {
        unsigned short* wfq = (unsigned short*)d_ws;
        unsigned short* wfp = wfq + WQ_ELEMS;
        prep_weights<<<48, 256, 0, stream>>>(Wqkv, Wproj, wfq, wfp);
        win_attn<0><<<8192, 256, 0, stream>>>(x, wfq, wfp, bqkv, bproj, out, wfq /*unused*/);
    }
}

// Round 7
// 386.509 us; speedup vs baseline: 8.2124x; 3.6801x over previous
//
#include <hip/hip_runtime.h>
#include <hip/hip_bf16.h>

// TinyLocalWindowAttention on MI355X (gfx950)
// x:(32,256,112,112) f32, 7x7 windows, 8192 windows; 1 block (4 waves) per window.
// bf16 MFMA 16x16x32. LDS 32KB static + 16KB dynamic pad = 48KB -> 3 blocks/CU
// (the measured L2-locality sweet spot: FETCH 226MB @3blk vs 830MB @5blk).
// Attention: S^T = mfma(K,Q); softmax fully in-register (no max, data-safe;
// pre-normalized P); PV A-frags built via ds_bpermute (no LDS round trip).
// Output: direct scatter f32 (wave-own cols; ~1.7x write amp at 3 blk/CU --
// cheaper than any decomposed path per rounds 4-6 measurements).

typedef short bf16x8 __attribute__((ext_vector_type(8)));   // 8 bf16 (4 VGPRs)
typedef float f32x4 __attribute__((ext_vector_type(4)));

static __device__ __forceinline__ unsigned short cvt1(float f) {
    __hip_bfloat16 h = __float2bfloat16(f);
    unsigned short u; __builtin_memcpy(&u, &h, 2); return u;
}
static __device__ __forceinline__ unsigned int cvt2(float a, float b) {
    float2 t; t.x = a; t.y = b;
    __hip_bfloat162 h = __float22bfloat162_rn(t);
    unsigned int u; __builtin_memcpy(&u, &h, 4); return u;
}
static __device__ __forceinline__ float bf2f(unsigned int hs) {
    return __uint_as_float(hs << 16);
}

#define WQ_ELEMS 65536LL
#define WP_ELEMS 32768LL

// ---- pre-pass: Wqkv[256][256], Wproj[128][256] f32 -> bf16 B-fragment arrays ----
__global__ void prep_weights(const float* __restrict__ Wqkv,
                             const float* __restrict__ Wproj,
                             unsigned short* __restrict__ wq,
                             unsigned short* __restrict__ wp) {
    int tid = blockIdx.x * 256 + threadIdx.x;
    if (tid < 8192) {                         // 16 ntiles * 8 ktiles * 64 lanes
        int lane = tid & 63, f = tid >> 6;
        int kt = f & 7, nt = f >> 3;
        int kbase = kt * 32 + (lane >> 4) * 8;
        int col = nt * 16 + (lane & 15);
        uint4 u;
        u.x = cvt2(Wqkv[(kbase + 0) * 256 + col], Wqkv[(kbase + 1) * 256 + col]);
        u.y = cvt2(Wqkv[(kbase + 2) * 256 + col], Wqkv[(kbase + 3) * 256 + col]);
        u.z = cvt2(Wqkv[(kbase + 4) * 256 + col], Wqkv[(kbase + 5) * 256 + col]);
        u.w = cvt2(Wqkv[(kbase + 6) * 256 + col], Wqkv[(kbase + 7) * 256 + col]);
        *reinterpret_cast<uint4*>(&wq[(long long)tid * 8]) = u;
    } else if (tid < 12288) {                 // 16 ntiles * 4 ktiles * 64 lanes
        int i2 = tid - 8192;
        int lane = i2 & 63, f = i2 >> 6;
        int kt = f & 3, nt = f >> 2;
        int kbase = kt * 32 + (lane >> 4) * 8;
        int col = nt * 16 + (lane & 15);
        uint4 u;
        u.x = cvt2(Wproj[(kbase + 0) * 256 + col], Wproj[(kbase + 1) * 256 + col]);
        u.y = cvt2(Wproj[(kbase + 2) * 256 + col], Wproj[(kbase + 3) * 256 + col]);
        u.z = cvt2(Wproj[(kbase + 4) * 256 + col], Wproj[(kbase + 5) * 256 + col]);
        u.w = cvt2(Wproj[(kbase + 6) * 256 + col], Wproj[(kbase + 7) * 256 + col]);
        *reinterpret_cast<uint4*>(&wp[(long long)i2 * 8]) = u;
    }
}

// LDS (static 32 KB; +16 KB dynamic pad at launch -> 3 blocks/CU):
//  A: xa[64][256] -> { q[64][64]@0, k[64][64]@4096, vT[4][32][64]@8192 }
//     -> o_s[64][128]@0 -> out_s[64][256]
// swizzle: elem(row,col,W) = row*W + (((col>>3) ^ (row&7))<<3) + (col&7)

__global__ __launch_bounds__(256, 3) void win_attn(
    const float* __restrict__ x,
    const unsigned short* __restrict__ wfq,
    const unsigned short* __restrict__ wfp,
    const float* __restrict__ bqkv,
    const float* __restrict__ bproj,
    float* __restrict__ out)
{
    __shared__ __align__(16) unsigned short A[16384];

    const int tid  = threadIdx.x;
    const int lane = tid & 63;
    const int wave = tid >> 6;
    const int lr   = lane & 15;       // row/col within 16-tile
    const int kg   = lane >> 4;       // k-group (0..3)

    // XCD swizzle: contiguous 1024 windows per XCD; consecutive L within a
    // band are dispatch-adjacent on the same XCD (write-merge locality).
    const int bid = (int)blockIdx.x;
    const int L   = (bid & 7) * 1024 + (bid >> 3);
    const int b   = L >> 8;
    const int rem = L & 255;
    const int h0 = (rem >> 4) * 7;
    const int w0 = (rem & 15) * 7;
    const int xwin = (b * 256) * 12544 + h0 * 112 + w0;

    // preload biases
    float bqv[4], bpv[4];
    #pragma unroll
    for (int nn = 0; nn < 4; ++nn) {
        bqv[nn] = bqkv[wave * 64 + nn * 16 + lr];
        bpv[nn] = bproj[wave * 64 + nn * 16 + lr];
    }

    // ---- phase A: zero pad rows 49..63, load x window -> xa (bf16) ----
    {
        uint4 z4 = uint4{0u, 0u, 0u, 0u};
        #pragma unroll
        for (int i = 0; i < 2; ++i)
            reinterpret_cast<uint4*>(&A[49 * 256])[tid + i * 256] = z4;
    }

    if (lane < 49) {
        const int lb = xwin + (lane / 7) * 112 + (lane % 7);
        #pragma unroll 4
        for (int it = 0; it < 16; ++it) {
            const int c0 = wave * 64 + it * 4;
            const float v0 = x[lb + (c0 + 0) * 12544];
            const float v1 = x[lb + (c0 + 1) * 12544];
            const float v2 = x[lb + (c0 + 2) * 12544];
            const float v3 = x[lb + (c0 + 3) * 12544];
            uint2 pk; pk.x = cvt2(v0, v1); pk.y = cvt2(v2, v3);
            const int e = lane * 256 + (((c0 >> 3) ^ (lane & 7)) << 3) + (c0 & 7);
            *reinterpret_cast<uint2*>(&A[e]) = pk;
        }
    }
    __syncthreads();   // (1) xa ready

    // ---- phase B: qkv = xa @ Wqkv ; wave w owns output cols [64w, 64w+64) ----
    f32x4 acc[4][4];
    #pragma unroll
    for (int m = 0; m < 4; ++m)
        #pragma unroll
        for (int nn = 0; nn < 4; ++nn)
            acc[m][nn] = f32x4{0.f, 0.f, 0.f, 0.f};

    #pragma unroll
    for (int kt = 0; kt < 8; ++kt) {
        bf16x8 a[4], bw[4];
        #pragma unroll
        for (int m = 0; m < 4; ++m) {
            const int row = lr + 16 * m;
            const int ch  = (kt * 4 + kg) ^ (row & 7);
            a[m] = *reinterpret_cast<const bf16x8*>(&A[row * 256 + ch * 8]);
        }
        #pragma unroll
        for (int nn = 0; nn < 4; ++nn) {
            const int nt = wave * 4 + nn;
            bw[nn] = *reinterpret_cast<const bf16x8*>(&wfq[((nt * 8 + kt) * 64 + lane) * 8]);
        }
        #pragma unroll
        for (int m = 0; m < 4; ++m)
            #pragma unroll
            for (int nn = 0; nn < 4; ++nn)
                acc[m][nn] = __builtin_amdgcn_mfma_f32_16x16x32_bf16(a[m], bw[nn], acc[m][nn], 0, 0, 0);
    }
    __syncthreads();   // (2) all waves done READING xa (q/k/vT overlay it)

    // epilogue: +bias; wave0 -> q@A[0), wave1 -> k@A[4096), waves 2,3 -> vT@A[8192)
    #pragma unroll
    for (int nn = 0; nn < 4; ++nn) {
        const int colg = wave * 64 + nn * 16 + lr;
        #pragma unroll
        for (int m = 0; m < 4; ++m)
            #pragma unroll
            for (int r = 0; r < 4; ++r) {
                const int row = kg * 4 + r + 16 * m;        // token
                const unsigned short hv = cvt1(acc[m][nn][r] + bqv[nn]);
                if (wave < 2) {
                    const int c = colg & 63;
                    A[(wave << 12) + row * 64 + (((c >> 3) ^ (row & 7)) << 3) + (c & 7)] = hv;
                } else {
                    const int vc = colg - 128;
                    const int hh = vc >> 5, d = vc & 31;
                    A[8192 + hh * 2048 + d * 64 + (((row >> 3) ^ (d & 7)) << 3) + (row & 7)] = hv;
                }
            }
    }
    __syncthreads();   // (3) q/k/vT ready

    // ---- attention, head h = wave; S^T = mfma(K, Q): lane holds P^T col for
    //      one q-token: col=lane&15=q-token, row=4kg+r=k-token ----
    const int h = wave;
    const bf16x8 zf = {0, 0, 0, 0, 0, 0, 0, 0};

    bf16x8 kf[4];
    #pragma unroll
    for (int km = 0; km < 4; ++km) {
        if (lane < 32) {
            const int row = lr + 16 * km;
            kf[km] = *reinterpret_cast<const bf16x8*>(
                &A[4096 + row * 64 + (((h * 2 + kg) ^ (row & 7)) << 3)]);
        } else kf[km] = zf;
    }
    bf16x8 vb[2][2];
    #pragma unroll
    for (int kt = 0; kt < 2; ++kt)
        #pragma unroll
        for (int nt = 0; nt < 2; ++nt) {
            const int d = lr + 16 * nt;
            const int ch = (kt * 4 + kg) ^ (d & 7);
            vb[kt][nt] = *reinterpret_cast<const bf16x8*>(&A[8192 + h * 2048 + d * 64 + ch * 8]);
        }

    // bpermute source addresses (bytes): srclane = 16*((2kg+{0,1})&3) + lr
    const int a0 = (((kg & 1) * 2)     * 16 + lr) * 4;
    const int a1 = (((kg & 1) * 2 + 1) * 16 + lr) * 4;

    f32x4 oacc[4][2];
    #pragma unroll
    for (int qn = 0; qn < 4; ++qn) {
        oacc[qn][0] = f32x4{0.f, 0.f, 0.f, 0.f};
        oacc[qn][1] = f32x4{0.f, 0.f, 0.f, 0.f};
    }
    const float C = 0.25f * 1.44269504f;    // SCALE * log2(e)

    #pragma unroll
    for (int qn = 0; qn < 4; ++qn) {
        bf16x8 qf;
        if (lane < 32) {
            const int row = lr + 16 * qn;
            qf = *reinterpret_cast<const bf16x8*>(
                &A[row * 64 + (((h * 2 + kg) ^ (row & 7)) << 3)]);
        } else qf = zf;

        f32x4 s[4];
        #pragma unroll
        for (int km = 0; km < 4; ++km) {
            f32x4 z = f32x4{0.f, 0.f, 0.f, 0.f};
            s[km] = __builtin_amdgcn_mfma_f32_16x16x32_bf16(kf[km], qf, z, 0, 0, 0);
        }

        float e[4][4];
        float sum = 0.f;
        #pragma unroll
        for (int km = 0; km < 4; ++km)
            #pragma unroll
            for (int r = 0; r < 4; ++r) {
                float v = __builtin_amdgcn_exp2f(s[km][r] * C);
                if (km == 3 && !(kg == 0 && r == 0)) v = 0.f;   // k-token 48 only
                e[km][r] = v;
                sum += v;
            }
        sum += __shfl_xor(sum, 16, 64);
        sum += __shfl_xor(sum, 32, 64);
        const float rs = __builtin_amdgcn_rcpf(sum);

        unsigned int D[4][2];
        #pragma unroll
        for (int km = 0; km < 4; ++km) {
            D[km][0] = cvt2(e[km][0] * rs, e[km][1] * rs);
            D[km][1] = cvt2(e[km][2] * rs, e[km][3] * rs);
        }

        #pragma unroll
        for (int kt = 0; kt < 2; ++kt) {
            const int klo = 2 * kt, khi = 2 * kt + 1;
            const unsigned int t0 = (unsigned)__builtin_amdgcn_ds_bpermute(a0, (int)D[klo][0]);
            const unsigned int u0 = (unsigned)__builtin_amdgcn_ds_bpermute(a0, (int)D[khi][0]);
            const unsigned int t1 = (unsigned)__builtin_amdgcn_ds_bpermute(a0, (int)D[klo][1]);
            const unsigned int u1 = (unsigned)__builtin_amdgcn_ds_bpermute(a0, (int)D[khi][1]);
            const unsigned int t2 = (unsigned)__builtin_amdgcn_ds_bpermute(a1, (int)D[klo][0]);
            const unsigned int u2 = (unsigned)__builtin_amdgcn_ds_bpermute(a1, (int)D[khi][0]);
            const unsigned int t3 = (unsigned)__builtin_amdgcn_ds_bpermute(a1, (int)D[klo][1]);
            const unsigned int u3 = (unsigned)__builtin_amdgcn_ds_bpermute(a1, (int)D[khi][1]);
            union { unsigned int u[4]; bf16x8 v; } pu;
            pu.u[0] = (kg < 2) ? t0 : u0;
            pu.u[1] = (kg < 2) ? t1 : u1;
            pu.u[2] = (kg < 2) ? t2 : u2;
            pu.u[3] = (kg < 2) ? t3 : u3;
            oacc[qn][0] = __builtin_amdgcn_mfma_f32_16x16x32_bf16(pu.v, vb[kt][0], oacc[qn][0], 0, 0, 0);
            oacc[qn][1] = __builtin_amdgcn_mfma_f32_16x16x32_bf16(pu.v, vb[kt][1], oacc[qn][1], 0, 0, 0);
        }
    }

    __syncthreads();   // (4) q/k reads done -> o_s overlays A[0..8192)

    #pragma unroll
    for (int qn = 0; qn < 4; ++qn)
        #pragma unroll
        for (int nt = 0; nt < 2; ++nt)
            #pragma unroll
            for (int r = 0; r < 4; ++r) {
                const int row = kg * 4 + r + 16 * qn;
                const int col = h * 32 + nt * 16 + lr;
                A[row * 128 + (((col >> 3) ^ (row & 7)) << 3) + (col & 7)] =
                    cvt1(oacc[qn][nt][r]);
            }
    __syncthreads();   // (5) o_s ready

    // ---- proj: out = o_s @ Wproj + bproj ----
    f32x4 pc[4][4];
    #pragma unroll
    for (int m = 0; m < 4; ++m)
        #pragma unroll
        for (int nn = 0; nn < 4; ++nn)
            pc[m][nn] = f32x4{0.f, 0.f, 0.f, 0.f};

    #pragma unroll
    for (int kt = 0; kt < 4; ++kt) {
        bf16x8 a[4], bw[4];
        #pragma unroll
        for (int m = 0; m < 4; ++m) {
            const int row = lr + 16 * m;
            const int ch = (kt * 4 + kg) ^ (row & 7);
            a[m] = *reinterpret_cast<const bf16x8*>(&A[row * 128 + ch * 8]);
        }
        #pragma unroll
        for (int nn = 0; nn < 4; ++nn) {
            const int nt = wave * 4 + nn;
            bw[nn] = *reinterpret_cast<const bf16x8*>(&wfp[((nt * 4 + kt) * 64 + lane) * 8]);
        }
        #pragma unroll
        for (int m = 0; m < 4; ++m)
            #pragma unroll
            for (int nn = 0; nn < 4; ++nn)
                pc[m][nn] = __builtin_amdgcn_mfma_f32_16x16x32_bf16(a[m], bw[nn], pc[m][nn], 0, 0, 0);
    }
    __syncthreads();   // (6) proj reads done -> out_s overlays everything

    // write out_s[64][256] into A
    #pragma unroll
    for (int nn = 0; nn < 4; ++nn) {
        const int colg = wave * 64 + nn * 16 + lr;
        #pragma unroll
        for (int m = 0; m < 4; ++m)
            #pragma unroll
            for (int r = 0; r < 4; ++r) {
                const int row = kg * 4 + r + 16 * m;
                A[row * 256 + (((colg >> 3) ^ (row & 7)) << 3) + (colg & 7)] = cvt1(pc[m][nn][r] + bpv[nn]);
            }
    }
    // no barrier: each wave re-reads only its own column range below
    __builtin_amdgcn_wave_barrier();

    // ---- store: same 7-contiguous-float pattern as the loads (wave-own cols) ----
    if (lane < 49) {
        const int lb = xwin + (lane / 7) * 112 + (lane % 7);
        #pragma unroll 4
        for (int it = 0; it < 16; ++it) {
            const int c0 = wave * 64 + it * 4;
            const int e = lane * 256 + (((c0 >> 3) ^ (lane & 7)) << 3) + (c0 & 7);
            const uint2 pk = *reinterpret_cast<const uint2*>(&A[e]);
            out[lb + (c0 + 0) * 12544] = bf2f(pk.x & 0xffffu);
            out[lb + (c0 + 1) * 12544] = bf2f(pk.x >> 16);
            out[lb + (c0 + 2) * 12544] = bf2f(pk.y & 0xffffu);
            out[lb + (c0 + 3) * 12544] = bf2f(pk.y >> 16);
        }
    }
}

extern "C" void kernel_launch(void* const* d_in, const int* in_sizes, int n_in,
                              void* d_out, int out_size, void* d_ws, size_t ws_size,
                              hipStream_t stream) {
    const float* x     = (const float*)d_in[0];
    const float* Wqkv  = (const float*)d_in[1];
    const float* bqkv  = (const float*)d_in[2];
    const float* Wproj = (const float*)d_in[3];
    const float* bproj = (const float*)d_in[4];
    float* out = (float*)d_out;

    unsigned short* wfq = (unsigned short*)d_ws;
    unsigned short* wfp = wfq + WQ_ELEMS;

    prep_weights<<<48, 256, 0, stream>>>(Wqkv, Wproj, wfq, wfp);
    // 16 KB dynamic LDS pad: static 32 KB + 16 KB = 48 KB -> exactly 3 blocks/CU
    win_attn<<<8192, 256, 16384, stream>>>(x, wfq, wfp, bqkv, bproj, out);
}